// Round 1
// baseline (250.582 us; speedup 1.0000x reference)
//
#include <hip/hip_runtime.h>

// ROI crop_and_resize: feature_map [8,64,64,256] f32 NHWC, rois [8,128,4] f32
// out [1024,14,14,256] f32.
//
// v2: time-phased channel-split XCD mapping.
// Read stream is 822 MB (4 corners x 1KB per output pixel) vs a 33.5 MB fm.
// Old map (1 image -> 1 XCD) put a 4 MB working set in a 4 MB L2: zero
// headroom -> thrash -> reads served from L3/HBM (~123 us kernel).
// New map: grid is split into two time phases (blocks dispatch ~in order):
//   phase 0 -> batches 0..3, phase 1 -> batches 4..7.
// Within a phase each batch is served by TWO XCDs split by channel half
// (xcd>>1 = batch-in-phase, xcd&1 = channels [0,128) vs [128,256)).
// Per-XCD hot set = 2 MB (half the channels of one image) = half of L2.
//
// A wave now covers 32 channel-groups, so it processes 2 output pixels:
// lanes 0..31 -> pixel p, lanes 32..63 -> pixel p+1. Loads are float4
// (16B/lane, 512B per half-wave segment); stores stay non-temporal so the
// 205 MB write stream doesn't evict fm.

#define B_   8
#define H_   64
#define W_   64
#define C4_  64      // 256 channels / 4
#define NROI 128
#define CH_  14
#define CW_  14
#define PIX_PER_BATCH (NROI * CH_ * CW_)       // 25088
#define NPIX (B_ * PIX_PER_BATCH)              // 200704
#define PIXHALVES_PER_BLOCK 8                  // 256 threads / 32 lanes
#define BLOCKS_PER_XCDPHASE (PIX_PER_BATCH / PIXHALVES_PER_BLOCK)  // 3136
#define BLOCKS_PER_PHASE (BLOCKS_PER_XCDPHASE * 8)                 // 25088
#define BLOCKS_TOTAL (BLOCKS_PER_PHASE * 2)                        // 50176

typedef float nfloat4 __attribute__((ext_vector_type(4)));  // native vec for nt-store

__global__ __launch_bounds__(256) void roi_crop_resize_kernel(
    const float4* __restrict__ fm,     // [8*64*64*64] float4
    const float*  __restrict__ rois,   // [1024*4]
    nfloat4*      __restrict__ out)    // [200704*64] float4
{
    int m     = (int)blockIdx.x;
    int phase = (m >= BLOCKS_PER_PHASE) ? 1 : 0;
    int mm    = m - phase * BLOCKS_PER_PHASE;
    int xcd   = mm & 7;          // round-robin block->XCD dispatch
    int slot  = mm >> 3;

    int batch = phase * 4 + (xcd >> 1);   // which image this XCD reads
    int half  = xcd & 1;                  // which channel half

    int tid = (int)threadIdx.x;
    int ph  = slot * PIXHALVES_PER_BLOCK + (tid >> 5);  // pixel within batch [0,25088)
    int cg  = half * 32 + (tid & 31);                   // channel group 0..63

    int j = ph % CW_;
    int t = ph / CW_;
    int i = t % CH_;
    int r = t / CH_;                      // roi within batch
    int n = batch * NROI + r;             // global roi index 0..1023
    int pix = batch * PIX_PER_BATCH + ph; // global output pixel 0..200703

    const float* box = rois + n * 4;
    float y1 = box[0], x1 = box[1], y2 = box[2], x2 = box[3];

    const float Hm1 = (float)(H_ - 1);
    const float Wm1 = (float)(W_ - 1);

    float h_scale = (y2 - y1) * Hm1 / (float)(CH_ - 1);
    float w_scale = (x2 - x1) * Wm1 / (float)(CW_ - 1);

    float in_y = y1 * Hm1 + (float)i * h_scale;
    float in_x = x1 * Wm1 + (float)j * w_scale;

    bool valid = (in_y >= 0.0f) & (in_y <= Hm1) & (in_x >= 0.0f) & (in_x <= Wm1);

    float fy = floorf(in_y);
    float fx = floorf(in_x);
    float cy = ceilf(in_y);
    float cx = ceilf(in_x);

    int ty = (int)fminf(fmaxf(fy, 0.0f), Hm1);
    int by = (int)fminf(fmaxf(cy, 0.0f), Hm1);
    int lx = (int)fminf(fmaxf(fx, 0.0f), Wm1);
    int rx = (int)fminf(fmaxf(cx, 0.0f), Wm1);

    float yl = in_y - fy;
    float xl = in_x - fx;

    int rowT = (batch * H_ + ty) * W_;
    int rowB = (batch * H_ + by) * W_;

    float4 tl = fm[(rowT + lx) * C4_ + cg];
    float4 tr = fm[(rowT + rx) * C4_ + cg];
    float4 bl = fm[(rowB + lx) * C4_ + cg];
    float4 br = fm[(rowB + rx) * C4_ + cg];

    float4 o;
    {
        float top, bot;
        top = tl.x + (tr.x - tl.x) * xl;
        bot = bl.x + (br.x - bl.x) * xl;
        o.x = top + (bot - top) * yl;
        top = tl.y + (tr.y - tl.y) * xl;
        bot = bl.y + (br.y - bl.y) * xl;
        o.y = top + (bot - top) * yl;
        top = tl.z + (tr.z - tl.z) * xl;
        bot = bl.z + (br.z - bl.z) * xl;
        o.z = top + (bot - top) * yl;
        top = tl.w + (tr.w - tl.w) * xl;
        bot = bl.w + (br.w - bl.w) * xl;
        o.w = top + (bot - top) * yl;
    }

    if (!valid) { o.x = 0.0f; o.y = 0.0f; o.z = 0.0f; o.w = 0.0f; }

    nfloat4 ov;
    ov.x = o.x; ov.y = o.y; ov.z = o.z; ov.w = o.w;
    __builtin_nontemporal_store(ov, &out[(size_t)pix * C4_ + cg]);
}

extern "C" void kernel_launch(void* const* d_in, const int* in_sizes, int n_in,
                              void* d_out, int out_size, void* d_ws, size_t ws_size,
                              hipStream_t stream) {
    const float4* fm   = (const float4*)d_in[0];
    const float*  rois = (const float*)d_in[1];
    nfloat4*      out  = (nfloat4*)d_out;

    roi_crop_resize_kernel<<<BLOCKS_TOTAL, 256, 0, stream>>>(fm, rois, out);
}

// Round 2
// 249.099 us; speedup vs baseline: 1.0060x; 1.0060x over previous
//
#include <hip/hip_runtime.h>

// ROI crop_and_resize: feature_map [8,64,64,256] f32 NHWC, rois [8,128,4] f32
// out [1024,14,14,256] f32.
//
// v3: plain stores (drop __builtin_nontemporal_store).
// Evidence: harness fill writes 822 MB in 126 us (6.5 TB/s, plain stores).
// Our kernel: 205.5 MB out with nt stores took ~124.5 us == exactly the
// time 822 MB takes at HBM write speed == 4x amplification of 205.5 MB,
// i.e. each 16B/lane nt store costs a full 64B burst (nt bypasses L2
// write-combining). Also explains v1==v2 neutrality: store path saturated,
// read mapping irrelevant.
//
// Keeps v2's time-phased channel-split XCD map (neutral, theoretically
// better once the store bottleneck is gone):
//   phase 0 -> batches 0..3, phase 1 -> batches 4..7 (blocks dispatch ~in order)
//   within a phase: xcd>>1 = batch-in-phase, xcd&1 = channel half
//   per-XCD read hot set = 2 MB (half the channels of one image).

#define B_   8
#define H_   64
#define W_   64
#define C4_  64      // 256 channels / 4
#define NROI 128
#define CH_  14
#define CW_  14
#define PIX_PER_BATCH (NROI * CH_ * CW_)       // 25088
#define NPIX (B_ * PIX_PER_BATCH)              // 200704
#define PIXHALVES_PER_BLOCK 8                  // 256 threads / 32 lanes
#define BLOCKS_PER_XCDPHASE (PIX_PER_BATCH / PIXHALVES_PER_BLOCK)  // 3136
#define BLOCKS_PER_PHASE (BLOCKS_PER_XCDPHASE * 8)                 // 25088
#define BLOCKS_TOTAL (BLOCKS_PER_PHASE * 2)                        // 50176

__global__ __launch_bounds__(256) void roi_crop_resize_kernel(
    const float4* __restrict__ fm,     // [8*64*64*64] float4
    const float*  __restrict__ rois,   // [1024*4]
    float4*       __restrict__ out)    // [200704*64] float4
{
    int m     = (int)blockIdx.x;
    int phase = (m >= BLOCKS_PER_PHASE) ? 1 : 0;
    int mm    = m - phase * BLOCKS_PER_PHASE;
    int xcd   = mm & 7;          // round-robin block->XCD dispatch
    int slot  = mm >> 3;

    int batch = phase * 4 + (xcd >> 1);   // which image this XCD reads
    int half  = xcd & 1;                  // which channel half

    int tid = (int)threadIdx.x;
    int ph  = slot * PIXHALVES_PER_BLOCK + (tid >> 5);  // pixel within batch [0,25088)
    int cg  = half * 32 + (tid & 31);                   // channel group 0..63

    int j = ph % CW_;
    int t = ph / CW_;
    int i = t % CH_;
    int r = t / CH_;                      // roi within batch
    int n = batch * NROI + r;             // global roi index 0..1023
    int pix = batch * PIX_PER_BATCH + ph; // global output pixel 0..200703

    const float* box = rois + n * 4;
    float y1 = box[0], x1 = box[1], y2 = box[2], x2 = box[3];

    const float Hm1 = (float)(H_ - 1);
    const float Wm1 = (float)(W_ - 1);

    float h_scale = (y2 - y1) * Hm1 / (float)(CH_ - 1);
    float w_scale = (x2 - x1) * Wm1 / (float)(CW_ - 1);

    float in_y = y1 * Hm1 + (float)i * h_scale;
    float in_x = x1 * Wm1 + (float)j * w_scale;

    bool valid = (in_y >= 0.0f) & (in_y <= Hm1) & (in_x >= 0.0f) & (in_x <= Wm1);

    float fy = floorf(in_y);
    float fx = floorf(in_x);
    float cy = ceilf(in_y);
    float cx = ceilf(in_x);

    int ty = (int)fminf(fmaxf(fy, 0.0f), Hm1);
    int by = (int)fminf(fmaxf(cy, 0.0f), Hm1);
    int lx = (int)fminf(fmaxf(fx, 0.0f), Wm1);
    int rx = (int)fminf(fmaxf(cx, 0.0f), Wm1);

    float yl = in_y - fy;
    float xl = in_x - fx;

    int rowT = (batch * H_ + ty) * W_;
    int rowB = (batch * H_ + by) * W_;

    float4 tl = fm[(rowT + lx) * C4_ + cg];
    float4 tr = fm[(rowT + rx) * C4_ + cg];
    float4 bl = fm[(rowB + lx) * C4_ + cg];
    float4 br = fm[(rowB + rx) * C4_ + cg];

    float4 o;
    {
        float top, bot;
        top = tl.x + (tr.x - tl.x) * xl;
        bot = bl.x + (br.x - bl.x) * xl;
        o.x = top + (bot - top) * yl;
        top = tl.y + (tr.y - tl.y) * xl;
        bot = bl.y + (br.y - bl.y) * xl;
        o.y = top + (bot - top) * yl;
        top = tl.z + (tr.z - tl.z) * xl;
        bot = bl.z + (br.z - bl.z) * xl;
        o.z = top + (bot - top) * yl;
        top = tl.w + (tr.w - tl.w) * xl;
        bot = bl.w + (br.w - bl.w) * xl;
        o.w = top + (bot - top) * yl;
    }

    if (!valid) { o.x = 0.0f; o.y = 0.0f; o.z = 0.0f; o.w = 0.0f; }

    out[(size_t)pix * C4_ + cg] = o;
}

extern "C" void kernel_launch(void* const* d_in, const int* in_sizes, int n_in,
                              void* d_out, int out_size, void* d_ws, size_t ws_size,
                              hipStream_t stream) {
    const float4* fm   = (const float4*)d_in[0];
    const float*  rois = (const float*)d_in[1];
    float4*       out  = (float4*)d_out;

    roi_crop_resize_kernel<<<BLOCKS_TOTAL, 256, 0, stream>>>(fm, rois, out);
}

// Round 3
// 247.057 us; speedup vs baseline: 1.0143x; 1.0083x over previous
//
#include <hip/hip_runtime.h>

// ROI crop_and_resize: feature_map [8,64,64,256] f32 NHWC, rois [8,128,4] f32
// out [1024,14,14,256] f32.
//
// v4: MLP experiment. Three prior variants (nt vs plain stores, three XCD
// locality maps) all land at 249.0-250.6 us total (+-0.3%) -> kernel is
// insensitive to store path and read locality. Component models (HBM 37us,
// L2 24us, VALU 11us) can't reach the ~120us observed kernel time, leaving
// latency/MLP or a fixed harness wall as the surviving theories.
// This version doubles per-wave memory-level parallelism:
//   - 2 output pixels per thread: same i, columns j0 and j0+7
//   - 8 independent gather loads in flight per wave (was 4)
//   - shared in_y/row/y-lerp math between the pixel pair
//   - grid halves: 25088 blocks of 256
// If dur_us doesn't move, the fixed-wall theory is confirmed (roofline).

#define B_   8
#define H_   64
#define W_   64
#define C4_  64      // 256 channels / 4
#define NROI 128
#define CH_  14
#define CW_  14
// wave-task = (roi, i, j0) with j0 in [0,7): covers pixels (i,j0),(i,j0+7)
#define TASKS_PER_ROI (CH_ * 7)                 // 98
#define NTASKS (B_ * NROI * TASKS_PER_ROI)      // 100352
#define WAVES_PER_BLOCK 4
#define BLOCKS_TOTAL (NTASKS / WAVES_PER_BLOCK) // 25088

__global__ __launch_bounds__(256) void roi_crop_resize_kernel(
    const float4* __restrict__ fm,     // [8*64*64*64] float4
    const float*  __restrict__ rois,   // [1024*4]
    float4*       __restrict__ out)    // [200704*64] float4
{
    int tid = (int)threadIdx.x;
    int wt  = (int)blockIdx.x * WAVES_PER_BLOCK + (tid >> 6);  // wave-task id
    int cg  = tid & 63;                                        // channel group

    int n  = wt / TASKS_PER_ROI;            // roi index 0..1023
    int t  = wt - n * TASKS_PER_ROI;
    int i  = t / 7;                         // output row 0..13
    int j0 = t - i * 7;                     // first column 0..6  (pair: j0, j0+7)
    int b  = n >> 7;                        // batch

    const float* box = rois + n * 4;
    float y1 = box[0], x1 = box[1], y2 = box[2], x2 = box[3];

    const float Hm1 = (float)(H_ - 1);
    const float Wm1 = (float)(W_ - 1);

    float h_scale = (y2 - y1) * Hm1 / (float)(CH_ - 1);
    float w_scale = (x2 - x1) * Wm1 / (float)(CW_ - 1);

    // ---- shared y path (same i for both pixels) ----
    float in_y = y1 * Hm1 + (float)i * h_scale;
    bool  vy   = (in_y >= 0.0f) & (in_y <= Hm1);
    float fy   = floorf(in_y);
    float cy   = ceilf(in_y);
    int   ty   = (int)fminf(fmaxf(fy, 0.0f), Hm1);
    int   by   = (int)fminf(fmaxf(cy, 0.0f), Hm1);
    float yl   = in_y - fy;
    int rowT   = (b * H_ + ty) * W_;
    int rowB   = (b * H_ + by) * W_;

    // ---- x path, pixel A (j0) ----
    float in_xa = x1 * Wm1 + (float)j0 * w_scale;
    bool  vxa   = (in_xa >= 0.0f) & (in_xa <= Wm1);
    float fxa   = floorf(in_xa);
    float cxa   = ceilf(in_xa);
    int   lxa   = (int)fminf(fmaxf(fxa, 0.0f), Wm1);
    int   rxa   = (int)fminf(fmaxf(cxa, 0.0f), Wm1);
    float xla   = in_xa - fxa;

    // ---- x path, pixel B (j0+7) ----
    float in_xb = x1 * Wm1 + (float)(j0 + 7) * w_scale;
    bool  vxb   = (in_xb >= 0.0f) & (in_xb <= Wm1);
    float fxb   = floorf(in_xb);
    float cxb   = ceilf(in_xb);
    int   lxb   = (int)fminf(fmaxf(fxb, 0.0f), Wm1);
    int   rxb   = (int)fminf(fmaxf(cxb, 0.0f), Wm1);
    float xlb   = in_xb - fxb;

    // ---- 8 independent gather loads (max MLP) ----
    float4 aTL = fm[(rowT + lxa) * C4_ + cg];
    float4 aTR = fm[(rowT + rxa) * C4_ + cg];
    float4 aBL = fm[(rowB + lxa) * C4_ + cg];
    float4 aBR = fm[(rowB + rxa) * C4_ + cg];
    float4 bTL = fm[(rowT + lxb) * C4_ + cg];
    float4 bTR = fm[(rowT + rxb) * C4_ + cg];
    float4 bBL = fm[(rowB + lxb) * C4_ + cg];
    float4 bBR = fm[(rowB + rxb) * C4_ + cg];

    bool va = vy & vxa;
    bool vb = vy & vxb;

    float4 oa, ob;
    {
        float top, bot;
        top = aTL.x + (aTR.x - aTL.x) * xla;
        bot = aBL.x + (aBR.x - aBL.x) * xla;
        oa.x = top + (bot - top) * yl;
        top = aTL.y + (aTR.y - aTL.y) * xla;
        bot = aBL.y + (aBR.y - aBL.y) * xla;
        oa.y = top + (bot - top) * yl;
        top = aTL.z + (aTR.z - aTL.z) * xla;
        bot = aBL.z + (aBR.z - aBL.z) * xla;
        oa.z = top + (bot - top) * yl;
        top = aTL.w + (aTR.w - aTL.w) * xla;
        bot = aBL.w + (aBR.w - aBL.w) * xla;
        oa.w = top + (bot - top) * yl;

        top = bTL.x + (bTR.x - bTL.x) * xlb;
        bot = bBL.x + (bBR.x - bBL.x) * xlb;
        ob.x = top + (bot - top) * yl;
        top = bTL.y + (bTR.y - bTL.y) * xlb;
        bot = bBL.y + (bBR.y - bBL.y) * xlb;
        ob.y = top + (bot - top) * yl;
        top = bTL.z + (bTR.z - bTL.z) * xlb;
        bot = bBL.z + (bBR.z - bBL.z) * xlb;
        ob.z = top + (bot - top) * yl;
        top = bTL.w + (bTR.w - bTL.w) * xlb;
        bot = bBL.w + (bBR.w - bBL.w) * xlb;
        ob.w = top + (bot - top) * yl;
    }

    if (!va) { oa.x = 0.0f; oa.y = 0.0f; oa.z = 0.0f; oa.w = 0.0f; }
    if (!vb) { ob.x = 0.0f; ob.y = 0.0f; ob.z = 0.0f; ob.w = 0.0f; }

    size_t basepix = ((size_t)n * CH_ + i) * CW_;
    out[(basepix + j0)     * C4_ + cg] = oa;
    out[(basepix + j0 + 7) * C4_ + cg] = ob;
}

extern "C" void kernel_launch(void* const* d_in, const int* in_sizes, int n_in,
                              void* d_out, int out_size, void* d_ws, size_t ws_size,
                              hipStream_t stream) {
    const float4* fm   = (const float4*)d_in[0];
    const float*  rois = (const float*)d_in[1];
    float4*       out  = (float4*)d_out;

    roi_crop_resize_kernel<<<BLOCKS_TOTAL, 256, 0, stream>>>(fm, rois, out);
}